// Round 16
// baseline (391.189 us; speedup 1.0000x reference)
//
#include <hip/hip_runtime.h>
#include <hip/hip_bf16.h>
#include <stdint.h>

// ---------- types ----------
typedef __attribute__((ext_vector_type(8))) short     bf16x8;  // MFMA A/B frag (4 VGPR)
typedef __attribute__((ext_vector_type(4))) float     f32x4;   // MFMA C/D frag

__device__ __forceinline__ unsigned short f2bf(float f) {
  unsigned int u = __float_as_uint(f);
  u += 0x7FFFu + ((u >> 16) & 1u);   // round-to-nearest-even
  return (unsigned short)(u >> 16);
}

__device__ __forceinline__ void async_cp16(const void* g, void* l) {
  __builtin_amdgcn_global_load_lds((const __attribute__((address_space(1))) void*)g,
                                   (__attribute__((address_space(3))) void*)l,
                                   16, 0, 0);
}

// ---------- merged fp32 -> bf16 conversion (one launch for x, wug-perm, wd) --
// float4-unit ranges: x [0, 7340032), wug [7340032, 14680064), wd [.., 18350080)
// wug permute: out row r: g = r>>5, w = r&31; src = g*16 + (w&15) + (w&16?2048:0)
// -> each 32-row group = 16 gate rows + 16 up rows of the same e-block.
__global__ __launch_bounds__(256) void cvt_all(const float* __restrict__ x,
                                               const float* __restrict__ wug,
                                               const float* __restrict__ wd,
                                               unsigned short* __restrict__ xb,
                                               unsigned short* __restrict__ wub,
                                               unsigned short* __restrict__ wdb) {
  int i = blockIdx.x * blockDim.x + threadIdx.x;
  const int stride = gridDim.x * blockDim.x;
  for (; i < 18350080; i += stride) {
    float4 v; ushort4* dp;
    if (i < 7340032) {
      v = ((const float4*)x)[i];
      dp = (ushort4*)xb + i;
    } else if (i < 14680064) {
      const int k = i - 7340032;
      const int r = k / 1792, c = k - r * 1792;
      const int g = r >> 5, w = r & 31;
      const int src = g * 16 + (w & 15) + ((w & 16) ? 2048 : 0);
      v = ((const float4*)wug)[(size_t)src * 1792 + c];
      dp = (ushort4*)wub + k;
    } else {
      const int k = i - 14680064;
      v = ((const float4*)wd)[k];
      dp = (ushort4*)wdb + k;
    }
    ushort4 o;
    o.x = f2bf(v.x); o.y = f2bf(v.y); o.z = f2bf(v.z); o.w = f2bf(v.w);
    *dp = o;
  }
}

// ---------- 256x256 NT bf16 GEMM: BK=64 dbuf, 4-phase DUAL-BARRIER schedule -
// Round-15 + the m201 mid-phase barrier (the one untested structural element):
//   phase = reads | stage | BARRIER | lgkmcnt(0) | setprio(1) 16 MFMA | barrier
// Mechanism: after the post-MFMA barrier, all waves issue the NEXT phase's
// ds_reads while the matrix pipe is still DRAINING this phase's MFMAs
// (s_barrier does not drain the MFMA pipe). By the next mid-phase barrier the
// reads have landed -> lgkm0 is free -> the next cluster issues back-to-back.
// Single-barrier phases (r9/r14/r15) serialize read-issue + lgkm-wait +
// MFMA-issue per wave: matrix busy ~155/280 ~ 55% = our measured plateau.
// NO sched_barrier(0) (m141/r7 poison). lgkm0 is safe: ds_reads are
// compiler-emitted, deps tracked; the inline wait is belt-and-braces.
// Per K-tile (BK=64): PhA Q00 (reads 12, stage 2), PhB Q01 (reads 4, stage 4,
// vmcnt(6) end), PhC Q11 (reads 8, stage 2), PhD Q10 (pure reg, vmcnt(2) end).
// Counted vmcnt only, never 0 except final tile (invariants proven r9/r14/r15).
// Swizzle (0-conflict, HW-verified): row r = 128B line; 16B phys slot p holds
// logical q = p ^ (r&7); staging pre-swizzles the per-lane GLOBAL source, LDS
// dest stays linear (m173).
// FUSE_SWIGLU: B rows pre-permuted so acc n in {0,2}=gate, {1,3}=up of the
// same e-cols -> h = silu(g)*u in-lane, write [M, N/2] bf16.
template <int K, int N, bool FUSE_SWIGLU>
__global__ __launch_bounds__(512, 1) void gemm_nt(const unsigned short* __restrict__ A,
                                                  const unsigned short* __restrict__ B,
                                                  void* __restrict__ Cv) {
  extern __shared__ char sm[];   // 131072 B: buf{0,1} x [A 32K | B 32K]
  constexpr int nbx = N / 256;
  constexpr int nwg = (4096 / 256) * nbx;
  constexpr size_t K2 = (size_t)K * 2;
  constexpr int nt = K / 64;     // K-tiles

  // T1: bijective XCD swizzle (nwg % 8 == 0 for both GEMMs)
  const int bid = blockIdx.x;
  constexpr int q8 = nwg / 8;
  const int swz = (bid & 7) * q8 + (bid >> 3);
  const int bx = swz % nbx, by = swz / nbx;
  const int row0 = by * 256, col0 = bx * 256;

  const int tid = threadIdx.x, wave = tid >> 6, lane = tid & 63;
  const int wr = wave >> 2, wc = wave & 3;       // wave 2x4 grid
  const int fr = lane & 15, fg = lane >> 4;      // fragment row / k-group

  // ---- staging setup: per thread 1 load per 8KB quarter (64 rows x 128B) ----
  const int l3 = lane >> 3, p7 = lane & 7;
  const int qgl = p7 ^ l3;                  // pre-swizzled logical 16B slot
  const char* srcA = (const char*)A + (size_t)(row0 + wave * 8 + l3) * K2 + qgl * 16;
  const char* srcB = (const char*)B + (size_t)(col0 + wave * 8 + l3) * K2 + qgl * 16;
  const int dstq = wave * 1024 + lane * 16; // linear dest within a quarter

#define STAGE_AQ(qa, tt, bufo) \
  async_cp16(srcA + (size_t)(qa) * 64 * K2 + (size_t)(tt) * 128, \
             sm + (bufo) + (qa) * 8192 + dstq)
#define STAGE_BQ(qb, tt, bufo) \
  async_cp16(srcB + (size_t)(qb) * 64 * K2 + (size_t)(tt) * 128, \
             sm + (bufo) + 32768 + (qb) * 8192 + dstq)

  // mid-phase fence: reads done by all waves; next MFMA cluster starts clean
#define MIDBAR() do {                                        \
    __builtin_amdgcn_s_barrier();                            \
    asm volatile("s_waitcnt lgkmcnt(0)" ::: "memory");       \
  } while (0)

  // ---- fragment read offsets (swizzled): row r byte = r*128 + ((kk*4+fg)^(r&7))*16
  const int s0 = ((fg) ^ (fr & 7)) << 4;
  const int s1 = ((4 + fg) ^ (fr & 7)) << 4;
  const int offAb = wr * 16384 + fr * 128;        // + mt*2048 + s[kk]
  const int offBb = 32768 + wc * 8192 + fr * 128; // + nt*2048 + s[kk]

  f32x4 acc[8][4];
#pragma unroll
  for (int m = 0; m < 8; ++m)
#pragma unroll
    for (int n = 0; n < 4; ++n) acc[m][n] = (f32x4){0.f, 0.f, 0.f, 0.f};

  // prologue: stage tile 0 (G_first 6, then G_late 2); drain G_first; sync
  STAGE_AQ(0, 0, 0); STAGE_AQ(2, 0, 0);
  STAGE_BQ(0, 0, 0); STAGE_BQ(1, 0, 0); STAGE_BQ(2, 0, 0); STAGE_BQ(3, 0, 0);
  STAGE_AQ(1, 0, 0); STAGE_AQ(3, 0, 0);
  asm volatile("s_waitcnt vmcnt(2)" ::: "memory");
  __builtin_amdgcn_s_barrier();

  // invariant at tile-t top: G_first(t) resident; own outstanding = G_late(t)=2
  for (int t = 0; t < nt; ++t) {
    const char* cur = sm + (t & 1) * 65536;
    const int nxo = ((t + 1) & 1) * 65536;
    const bool more = (t + 1 < nt);

    bf16x8 a0[4][2], b0[2][2], b1[2][2], a1[4][2];

    // ======== phase A: Q00 (m0-3 x n0-1) ========
#pragma unroll
    for (int mt = 0; mt < 4; ++mt) {
      a0[mt][0] = *(const bf16x8*)(cur + offAb + mt * 2048 + s0);
      a0[mt][1] = *(const bf16x8*)(cur + offAb + mt * 2048 + s1);
    }
#pragma unroll
    for (int n = 0; n < 2; ++n) {
      b0[n][0] = *(const bf16x8*)(cur + offBb + n * 2048 + s0);
      b0[n][1] = *(const bf16x8*)(cur + offBb + n * 2048 + s1);
    }
    if (more) { STAGE_AQ(0, t + 1, nxo); STAGE_AQ(2, t + 1, nxo); }
    MIDBAR();
    __builtin_amdgcn_s_setprio(1);
#pragma unroll
    for (int kk = 0; kk < 2; ++kk)
#pragma unroll
      for (int mt = 0; mt < 4; ++mt)
#pragma unroll
        for (int n = 0; n < 2; ++n)
          acc[mt][n] = __builtin_amdgcn_mfma_f32_16x16x32_bf16(a0[mt][kk], b0[n][kk], acc[mt][n], 0, 0, 0);
    __builtin_amdgcn_s_setprio(0);
    __builtin_amdgcn_s_barrier();

    // ======== phase B: Q01 (m0-3 x n2-3) ========
#pragma unroll
    for (int n = 0; n < 2; ++n) {
      b1[n][0] = *(const bf16x8*)(cur + offBb + (n + 2) * 2048 + s0);
      b1[n][1] = *(const bf16x8*)(cur + offBb + (n + 2) * 2048 + s1);
    }
    if (more) {
      STAGE_BQ(0, t + 1, nxo); STAGE_BQ(1, t + 1, nxo);
      STAGE_BQ(2, t + 1, nxo); STAGE_BQ(3, t + 1, nxo);
    }
    MIDBAR();
    __builtin_amdgcn_s_setprio(1);
#pragma unroll
    for (int kk = 0; kk < 2; ++kk)
#pragma unroll
      for (int mt = 0; mt < 4; ++mt)
#pragma unroll
        for (int n = 0; n < 2; ++n)
          acc[mt][n + 2] = __builtin_amdgcn_mfma_f32_16x16x32_bf16(a0[mt][kk], b1[n][kk], acc[mt][n + 2], 0, 0, 0);
    __builtin_amdgcn_s_setprio(0);
    if (more) { asm volatile("s_waitcnt vmcnt(6)" ::: "memory"); }  // G_late(t) resident
    else      { asm volatile("s_waitcnt vmcnt(0)" ::: "memory"); }
    __builtin_amdgcn_s_barrier();

    // ======== phase C: Q11 (m4-7 x n2-3) ========
#pragma unroll
    for (int mt = 0; mt < 4; ++mt) {
      a1[mt][0] = *(const bf16x8*)(cur + offAb + (mt + 4) * 2048 + s0);
      a1[mt][1] = *(const bf16x8*)(cur + offAb + (mt + 4) * 2048 + s1);
    }
    if (more) { STAGE_AQ(1, t + 1, nxo); STAGE_AQ(3, t + 1, nxo); }
    MIDBAR();
    __builtin_amdgcn_s_setprio(1);
#pragma unroll
    for (int kk = 0; kk < 2; ++kk)
#pragma unroll
      for (int mt = 0; mt < 4; ++mt)
#pragma unroll
        for (int n = 0; n < 2; ++n)
          acc[mt + 4][n + 2] = __builtin_amdgcn_mfma_f32_16x16x32_bf16(a1[mt][kk], b1[n][kk], acc[mt + 4][n + 2], 0, 0, 0);
    __builtin_amdgcn_s_setprio(0);
    __builtin_amdgcn_s_barrier();

    // ======== phase D: Q10 (m4-7 x n0-1) — pure register ========
    __builtin_amdgcn_s_setprio(1);
#pragma unroll
    for (int kk = 0; kk < 2; ++kk)
#pragma unroll
      for (int mt = 0; mt < 4; ++mt)
#pragma unroll
        for (int n = 0; n < 2; ++n)
          acc[mt + 4][n] = __builtin_amdgcn_mfma_f32_16x16x32_bf16(a1[mt][kk], b0[n][kk], acc[mt + 4][n], 0, 0, 0);
    __builtin_amdgcn_s_setprio(0);
    if (more) {
      asm volatile("s_waitcnt vmcnt(2)" ::: "memory");  // G_first(t+1) resident
      __builtin_amdgcn_s_barrier();
    }
  }
#undef STAGE_AQ
#undef STAGE_BQ
#undef MIDBAR

  // ---- epilogue: C/D layout col = lane&15, row = (lane>>4)*4 + j (m89-verified) ----
  const int rowb = row0 + wr * 128 + fg * 4;
  if (FUSE_SWIGLU) {
    // acc n in {0,2}: gate; {1,3}: up, same e-cols (pre-permuted B)
    unsigned short* Hp = (unsigned short*)Cv;
    const int ecb = ((col0 + wc * 64) >> 1) + fr;
#pragma unroll
    for (int m = 0; m < 8; ++m)
#pragma unroll
      for (int p = 0; p < 2; ++p)
#pragma unroll
        for (int j = 0; j < 4; ++j) {
          const float gv = acc[m][2 * p][j];
          const float uv = acc[m][2 * p + 1][j];
          const float s  = gv / (1.0f + __expf(-gv));
          Hp[(size_t)(rowb + m * 16 + j) * (N / 2) + (ecb + p * 16)] = f2bf(s * uv);
        }
  } else {
    float* Cp = (float*)Cv;
    const int colb = col0 + wc * 64 + fr;
#pragma unroll
    for (int m = 0; m < 8; ++m)
#pragma unroll
      for (int n = 0; n < 4; ++n)
#pragma unroll
        for (int j = 0; j < 4; ++j)
          Cp[(size_t)(rowb + m * 16 + j) * N + (colb + n * 16)] = acc[m][n][j];
  }
}

// ---------- launch ----------
extern "C" void kernel_launch(void* const* d_in, const int* in_sizes, int n_in,
                              void* d_out, int out_size, void* d_ws, size_t ws_size,
                              hipStream_t stream) {
  const int M = 4096, K = 7168, E = 2048;

  const float* x   = (const float*)d_in[0];  // [M,K]
  const float* wug = (const float*)d_in[1];  // [2E,K]
  const float* wd  = (const float*)d_in[2];  // [K,E]
  float* out = (float*)d_out;                // [M,K]

  // workspace layout (bytes)
  char* ws = (char*)d_ws;
  unsigned short* xb  = (unsigned short*)(ws);               //  58,720,256
  unsigned short* wub = (unsigned short*)(ws + 58720256);    //  58,720,256 (permuted)
  unsigned short* wdb = (unsigned short*)(ws + 117440512);   //  29,360,128
  unsigned short* h   = (unsigned short*)(ws + 146800640);   //  16,777,216
  if (ws_size < 163577856) return;                           // need ~156 MiB

  // allow 128 KiB dynamic LDS (host-side calls, safe under graph capture)
  hipFuncSetAttribute((const void*)gemm_nt<7168, 4096, true>,
                      hipFuncAttributeMaxDynamicSharedMemorySize, 131072);
  hipFuncSetAttribute((const void*)gemm_nt<2048, 7168, false>,
                      hipFuncAttributeMaxDynamicSharedMemorySize, 131072);

  // 1) cast inputs to bf16 (single merged launch; wug with gate/up permutation)
  cvt_all<<<2048, 256, 0, stream>>>(x, wug, wd, xb, wub, wdb);

  // 2) h = swiglu(x @ w_up_gate^T) fused   [4096, 2048] bf16  (16x16 = 256 blocks)
  gemm_nt<7168, 4096, true><<<256, 512, 131072, stream>>>(xb, wub, h);

  // 3) out = h @ w_down^T     [4096, 7168] fp32  (16x28 = 448 blocks)
  gemm_nt<2048, 7168, false><<<448, 512, 131072, stream>>>(h, wdb, out);
}

// Round 17
// 371.626 us; speedup vs baseline: 1.0526x; 1.0526x over previous
//
#include <hip/hip_runtime.h>
#include <hip/hip_bf16.h>
#include <stdint.h>

// ---------- types ----------
typedef __attribute__((ext_vector_type(8))) short     bf16x8;  // MFMA A/B frag (4 VGPR)
typedef __attribute__((ext_vector_type(4))) float     f32x4;   // MFMA C/D frag

__device__ __forceinline__ unsigned short f2bf(float f) {
  unsigned int u = __float_as_uint(f);
  u += 0x7FFFu + ((u >> 16) & 1u);   // round-to-nearest-even
  return (unsigned short)(u >> 16);
}

__device__ __forceinline__ void async_cp16(const void* g, void* l) {
  __builtin_amdgcn_global_load_lds((const __attribute__((address_space(1))) void*)g,
                                   (__attribute__((address_space(3))) void*)l,
                                   16, 0, 0);
}

// ---------- merged fp32 -> bf16 conversion (one launch for x, wug-perm, wd) --
// float4-unit ranges: x [0, 7340032), wug [7340032, 14680064), wd [.., 18350080)
// wug permute: out row r: g = r>>5, w = r&31; src = g*16 + (w&15) + (w&16?2048:0)
// -> each 32-row group = 16 gate rows + 16 up rows of the same e-block.
__global__ __launch_bounds__(256) void cvt_all(const float* __restrict__ x,
                                               const float* __restrict__ wug,
                                               const float* __restrict__ wd,
                                               unsigned short* __restrict__ xb,
                                               unsigned short* __restrict__ wub,
                                               unsigned short* __restrict__ wdb) {
  int i = blockIdx.x * blockDim.x + threadIdx.x;
  const int stride = gridDim.x * blockDim.x;
  for (; i < 18350080; i += stride) {
    float4 v; ushort4* dp;
    if (i < 7340032) {
      v = ((const float4*)x)[i];
      dp = (ushort4*)xb + i;
    } else if (i < 14680064) {
      const int k = i - 7340032;
      const int r = k / 1792, c = k - r * 1792;
      const int g = r >> 5, w = r & 31;
      const int src = g * 16 + (w & 15) + ((w & 16) ? 2048 : 0);
      v = ((const float4*)wug)[(size_t)src * 1792 + c];
      dp = (ushort4*)wub + k;
    } else {
      const int k = i - 14680064;
      v = ((const float4*)wd)[k];
      dp = (ushort4*)wdb + k;
    }
    ushort4 o;
    o.x = f2bf(v.x); o.y = f2bf(v.y); o.z = f2bf(v.z); o.w = f2bf(v.w);
    *dp = o;
  }
}

// ---------- 256x256 NT bf16 GEMM: BK=64 dbuf, 4-PHASE quadrant schedule ----
// SESSION BEST (round-15: 372.0us total; GEMM1 203.5us, 1182 TF, MfmaUtil
// 54.3%, SQ_LDS_BANK_CONFLICT = 0, VGPR 112, no spill). Reverted after the
// round-16 dual-barrier experiment regressed (226us/48%).
// C[m,n] = sum_k A[m,k]*B[n,k]. 512 thr = 8 waves (2Mx4N), wave-tile 128x64.
// Per K-tile (BK=64), per wave (quadrant order Q00,Q01,Q11,Q10):
//   PhA: read a0 (8 b128) + b0 (4); stage A0,A2(t+1)=2; 16 MFMA; barrier
//   PhB: read b1 (4);  stage B0..B3(t+1)=4; 16 MFMA; vmcnt(6); barrier
//        [outstanding 8 = G_late(t) 2 + 6 of t+1 -> drains G_late(t)]
//   PhC: read a1 (8);  stage A1,A3(t+1)=2; 16 MFMA; barrier
//   PhD: 16 MFMA (pure register: a1 x b0); vmcnt(2); barrier
//        [drains the 6 G_first(t+1) loads -> resident for t+1 PhA reads]
// Mechanism (m201/T3): each cluster's MFMA issue overlaps the NEXT phase's
// ds_reads via bounded wave slip; single barrier per phase preserves that
// slip (r16's pre-MFMA rendezvous barrier removed it -> regression).
// Counted vmcnt only, never 0 except the final tile. The compiler emits
// fine-grained lgkmcnt for ds_read->MFMA (m97) — no hand waits, no
// sched_barrier (m141/r7 poison).
// Swizzle (0-conflict, HW-verified): row r = 128B line; 16B phys slot p holds
// logical q = p ^ (r&7); staging pre-swizzles the per-lane GLOBAL source, LDS
// dest stays linear (m173).
// FUSE_SWIGLU: B rows pre-permuted so acc n in {0,2}=gate, {1,3}=up of the
// same e-cols -> h = silu(g)*u in-lane, write [M, N/2] bf16.
template <int K, int N, bool FUSE_SWIGLU>
__global__ __launch_bounds__(512, 1) void gemm_nt(const unsigned short* __restrict__ A,
                                                  const unsigned short* __restrict__ B,
                                                  void* __restrict__ Cv) {
  extern __shared__ char sm[];   // 131072 B: buf{0,1} x [A 32K | B 32K]
  constexpr int nbx = N / 256;
  constexpr int nwg = (4096 / 256) * nbx;
  constexpr size_t K2 = (size_t)K * 2;
  constexpr int nt = K / 64;     // K-tiles

  // T1: bijective XCD swizzle (nwg % 8 == 0 for both GEMMs)
  const int bid = blockIdx.x;
  constexpr int q8 = nwg / 8;
  const int swz = (bid & 7) * q8 + (bid >> 3);
  const int bx = swz % nbx, by = swz / nbx;
  const int row0 = by * 256, col0 = bx * 256;

  const int tid = threadIdx.x, wave = tid >> 6, lane = tid & 63;
  const int wr = wave >> 2, wc = wave & 3;       // wave 2x4 grid
  const int fr = lane & 15, fg = lane >> 4;      // fragment row / k-group

  // ---- staging setup: per thread 1 load per 8KB quarter (64 rows x 128B) ----
  const int l3 = lane >> 3, p7 = lane & 7;
  const int qgl = p7 ^ l3;                  // pre-swizzled logical 16B slot
  const char* srcA = (const char*)A + (size_t)(row0 + wave * 8 + l3) * K2 + qgl * 16;
  const char* srcB = (const char*)B + (size_t)(col0 + wave * 8 + l3) * K2 + qgl * 16;
  const int dstq = wave * 1024 + lane * 16; // linear dest within a quarter

#define STAGE_AQ(qa, tt, bufo) \
  async_cp16(srcA + (size_t)(qa) * 64 * K2 + (size_t)(tt) * 128, \
             sm + (bufo) + (qa) * 8192 + dstq)
#define STAGE_BQ(qb, tt, bufo) \
  async_cp16(srcB + (size_t)(qb) * 64 * K2 + (size_t)(tt) * 128, \
             sm + (bufo) + 32768 + (qb) * 8192 + dstq)

  // ---- fragment read offsets (swizzled): row r byte = r*128 + ((kk*4+fg)^(r&7))*16
  const int s0 = ((fg) ^ (fr & 7)) << 4;
  const int s1 = ((4 + fg) ^ (fr & 7)) << 4;
  const int offAb = wr * 16384 + fr * 128;        // + mt*2048 + s[kk]
  const int offBb = 32768 + wc * 8192 + fr * 128; // + nt*2048 + s[kk]

  f32x4 acc[8][4];
#pragma unroll
  for (int m = 0; m < 8; ++m)
#pragma unroll
    for (int n = 0; n < 4; ++n) acc[m][n] = (f32x4){0.f, 0.f, 0.f, 0.f};

  // prologue: stage tile 0 (G_first 6, then G_late 2); drain G_first; sync
  STAGE_AQ(0, 0, 0); STAGE_AQ(2, 0, 0);
  STAGE_BQ(0, 0, 0); STAGE_BQ(1, 0, 0); STAGE_BQ(2, 0, 0); STAGE_BQ(3, 0, 0);
  STAGE_AQ(1, 0, 0); STAGE_AQ(3, 0, 0);
  asm volatile("s_waitcnt vmcnt(2)" ::: "memory");
  __builtin_amdgcn_s_barrier();

  // invariant at tile-t top: G_first(t) resident; own outstanding = G_late(t)=2
  for (int t = 0; t < nt; ++t) {
    const char* cur = sm + (t & 1) * 65536;
    const int nxo = ((t + 1) & 1) * 65536;
    const bool more = (t + 1 < nt);

    bf16x8 a0[4][2], b0[2][2], b1[2][2], a1[4][2];

    // ======== phase A: Q00 (m0-3 x n0-1) ========
#pragma unroll
    for (int mt = 0; mt < 4; ++mt) {
      a0[mt][0] = *(const bf16x8*)(cur + offAb + mt * 2048 + s0);
      a0[mt][1] = *(const bf16x8*)(cur + offAb + mt * 2048 + s1);
    }
#pragma unroll
    for (int n = 0; n < 2; ++n) {
      b0[n][0] = *(const bf16x8*)(cur + offBb + n * 2048 + s0);
      b0[n][1] = *(const bf16x8*)(cur + offBb + n * 2048 + s1);
    }
    if (more) { STAGE_AQ(0, t + 1, nxo); STAGE_AQ(2, t + 1, nxo); }
    __builtin_amdgcn_s_setprio(1);
#pragma unroll
    for (int kk = 0; kk < 2; ++kk)
#pragma unroll
      for (int mt = 0; mt < 4; ++mt)
#pragma unroll
        for (int n = 0; n < 2; ++n)
          acc[mt][n] = __builtin_amdgcn_mfma_f32_16x16x32_bf16(a0[mt][kk], b0[n][kk], acc[mt][n], 0, 0, 0);
    __builtin_amdgcn_s_setprio(0);
    __builtin_amdgcn_s_barrier();

    // ======== phase B: Q01 (m0-3 x n2-3) ========
#pragma unroll
    for (int n = 0; n < 2; ++n) {
      b1[n][0] = *(const bf16x8*)(cur + offBb + (n + 2) * 2048 + s0);
      b1[n][1] = *(const bf16x8*)(cur + offBb + (n + 2) * 2048 + s1);
    }
    if (more) {
      STAGE_BQ(0, t + 1, nxo); STAGE_BQ(1, t + 1, nxo);
      STAGE_BQ(2, t + 1, nxo); STAGE_BQ(3, t + 1, nxo);
    }
    __builtin_amdgcn_s_setprio(1);
#pragma unroll
    for (int kk = 0; kk < 2; ++kk)
#pragma unroll
      for (int mt = 0; mt < 4; ++mt)
#pragma unroll
        for (int n = 0; n < 2; ++n)
          acc[mt][n + 2] = __builtin_amdgcn_mfma_f32_16x16x32_bf16(a0[mt][kk], b1[n][kk], acc[mt][n + 2], 0, 0, 0);
    __builtin_amdgcn_s_setprio(0);
    if (more) { asm volatile("s_waitcnt vmcnt(6)" ::: "memory"); }  // G_late(t) resident
    else      { asm volatile("s_waitcnt vmcnt(0)" ::: "memory"); }
    __builtin_amdgcn_s_barrier();

    // ======== phase C: Q11 (m4-7 x n2-3) ========
#pragma unroll
    for (int mt = 0; mt < 4; ++mt) {
      a1[mt][0] = *(const bf16x8*)(cur + offAb + (mt + 4) * 2048 + s0);
      a1[mt][1] = *(const bf16x8*)(cur + offAb + (mt + 4) * 2048 + s1);
    }
    if (more) { STAGE_AQ(1, t + 1, nxo); STAGE_AQ(3, t + 1, nxo); }
    __builtin_amdgcn_s_setprio(1);
#pragma unroll
    for (int kk = 0; kk < 2; ++kk)
#pragma unroll
      for (int mt = 0; mt < 4; ++mt)
#pragma unroll
        for (int n = 0; n < 2; ++n)
          acc[mt + 4][n + 2] = __builtin_amdgcn_mfma_f32_16x16x32_bf16(a1[mt][kk], b1[n][kk], acc[mt + 4][n + 2], 0, 0, 0);
    __builtin_amdgcn_s_setprio(0);
    __builtin_amdgcn_s_barrier();

    // ======== phase D: Q10 (m4-7 x n0-1) — pure register ========
    __builtin_amdgcn_s_setprio(1);
#pragma unroll
    for (int kk = 0; kk < 2; ++kk)
#pragma unroll
      for (int mt = 0; mt < 4; ++mt)
#pragma unroll
        for (int n = 0; n < 2; ++n)
          acc[mt + 4][n] = __builtin_amdgcn_mfma_f32_16x16x32_bf16(a1[mt][kk], b0[n][kk], acc[mt + 4][n], 0, 0, 0);
    __builtin_amdgcn_s_setprio(0);
    if (more) {
      asm volatile("s_waitcnt vmcnt(2)" ::: "memory");  // G_first(t+1) resident
      __builtin_amdgcn_s_barrier();
    }
  }
#undef STAGE_AQ
#undef STAGE_BQ

  // ---- epilogue: C/D layout col = lane&15, row = (lane>>4)*4 + j (m89-verified) ----
  const int rowb = row0 + wr * 128 + fg * 4;
  if (FUSE_SWIGLU) {
    // acc n in {0,2}: gate; {1,3}: up, same e-cols (pre-permuted B)
    unsigned short* Hp = (unsigned short*)Cv;
    const int ecb = ((col0 + wc * 64) >> 1) + fr;
#pragma unroll
    for (int m = 0; m < 8; ++m)
#pragma unroll
      for (int p = 0; p < 2; ++p)
#pragma unroll
        for (int j = 0; j < 4; ++j) {
          const float gv = acc[m][2 * p][j];
          const float uv = acc[m][2 * p + 1][j];
          const float s  = gv / (1.0f + __expf(-gv));
          Hp[(size_t)(rowb + m * 16 + j) * (N / 2) + (ecb + p * 16)] = f2bf(s * uv);
        }
  } else {
    float* Cp = (float*)Cv;
    const int colb = col0 + wc * 64 + fr;
#pragma unroll
    for (int m = 0; m < 8; ++m)
#pragma unroll
      for (int n = 0; n < 4; ++n)
#pragma unroll
        for (int j = 0; j < 4; ++j)
          Cp[(size_t)(rowb + m * 16 + j) * N + (colb + n * 16)] = acc[m][n][j];
  }
}

// ---------- launch ----------
extern "C" void kernel_launch(void* const* d_in, const int* in_sizes, int n_in,
                              void* d_out, int out_size, void* d_ws, size_t ws_size,
                              hipStream_t stream) {
  const int M = 4096, K = 7168, E = 2048;

  const float* x   = (const float*)d_in[0];  // [M,K]
  const float* wug = (const float*)d_in[1];  // [2E,K]
  const float* wd  = (const float*)d_in[2];  // [K,E]
  float* out = (float*)d_out;                // [M,K]

  // workspace layout (bytes)
  char* ws = (char*)d_ws;
  unsigned short* xb  = (unsigned short*)(ws);               //  58,720,256
  unsigned short* wub = (unsigned short*)(ws + 58720256);    //  58,720,256 (permuted)
  unsigned short* wdb = (unsigned short*)(ws + 117440512);   //  29,360,128
  unsigned short* h   = (unsigned short*)(ws + 146800640);   //  16,777,216
  if (ws_size < 163577856) return;                           // need ~156 MiB

  // allow 128 KiB dynamic LDS (host-side calls, safe under graph capture)
  hipFuncSetAttribute((const void*)gemm_nt<7168, 4096, true>,
                      hipFuncAttributeMaxDynamicSharedMemorySize, 131072);
  hipFuncSetAttribute((const void*)gemm_nt<2048, 7168, false>,
                      hipFuncAttributeMaxDynamicSharedMemorySize, 131072);

  // 1) cast inputs to bf16 (single merged launch; wug with gate/up permutation)
  cvt_all<<<2048, 256, 0, stream>>>(x, wug, wd, xb, wub, wdb);

  // 2) h = swiglu(x @ w_up_gate^T) fused   [4096, 2048] bf16  (16x16 = 256 blocks)
  gemm_nt<7168, 4096, true><<<256, 512, 131072, stream>>>(xb, wub, h);

  // 3) out = h @ w_down^T     [4096, 7168] fp32  (16x28 = 448 blocks)
  gemm_nt<2048, 7168, false><<<448, 512, 131072, stream>>>(h, wdb, out);
}